// Round 1
// 265.680 us; speedup vs baseline: 1.0092x; 1.0092x over previous
//
#include <hip/hip_runtime.h>
#include <math.h>

// InputSequenceNormalization: x[B,F,T] fp32, lengths[B] fp32.
// n_b = round(lengths[b]*T); per (b,f) row: mean/std over first n_b frames
// (std unbiased ddof=1, clamped at 1e-10), normalize ALL T frames.
//
// One block per (b,f) row. BLOCK=256 (4 waves) so 8 blocks/CU co-reside
// (vs 4 with BLOCK=512): the per-block load->vmcnt(0)->reduce->barrier
// bubble is hidden by 7 other blocks instead of 3. Row held entirely in
// registers (8 float4/thread) so x is read from HBM exactly once.
// var = (ss - s^2/n)/(n-1); fp32 error ~1e-5, threshold 0.109.
// Nontemporal load/store: x read once, out never re-read -> keep L2 clean.
// __launch_bounds__(256, 8) pins VGPR <= 64 for the full 32 waves/CU.

#define ROW_T 8000
#define TV (ROW_T / 4)          // 2000 float4 per row
#define BLOCK 256
#define WAVES (BLOCK / 64)      // 4
#define VPT 8                   // ceil(2000/256) = 8 float4 per thread
#define EPS 1e-10f

typedef float v4f __attribute__((ext_vector_type(4)));

__global__ __launch_bounds__(BLOCK, 8) void isn_kernel(
        const float* __restrict__ x,
        const float* __restrict__ lengths,
        float* __restrict__ out,
        int F) {
    __shared__ float2 lds[WAVES];

    const int row = blockIdx.x;            // row = b*F + f
    const int b = row / F;
    const v4f* __restrict__ xr = (const v4f*)(x + (size_t)row * ROW_T);
    v4f* __restrict__ outr = (v4f*)(out + (size_t)row * ROW_T);
    const int tid = threadIdx.x;

    // valid frame count (jnp.round == rintf: half-to-even)
    const int n = (int)rintf(lengths[b] * (float)ROW_T);
    const float nf = (float)n;

    // ---- load row into registers (single HBM read of x, nontemporal) ----
    v4f v[VPT];
    #pragma unroll
    for (int it = 0; it < VPT; ++it) {
        const int idx = tid + it * BLOCK;
        if (idx < TV) v[it] = __builtin_nontemporal_load(&xr[idx]);
    }

    // ---- fused masked sum + sumsq ----
    float s = 0.0f, ss = 0.0f;
    #pragma unroll
    for (int it = 0; it < VPT; ++it) {
        const int base = (tid + it * BLOCK) * 4;
        if (base < ROW_T) {
            #pragma unroll
            for (int j = 0; j < 4; ++j) {
                const float xv = (base + j < n) ? v[it][j] : 0.0f;
                s += xv;
                ss = fmaf(xv, xv, ss);
            }
        }
    }

    // ---- one block reduction of (s, ss): 64-lane shuffle + 4-wave LDS ----
    #pragma unroll
    for (int off = 32; off > 0; off >>= 1) {
        s  += __shfl_down(s, off, 64);
        ss += __shfl_down(ss, off, 64);
    }
    const int wave = tid >> 6;
    const int lane = tid & 63;
    if (lane == 0) lds[wave] = make_float2(s, ss);
    __syncthreads();
    float rs = 0.0f, rss = 0.0f;
    #pragma unroll
    for (int i = 0; i < WAVES; ++i) { rs += lds[i].x; rss += lds[i].y; }

    const float mean = rs / nf;
    const float var = (rss - rs * rs / nf) / (nf - 1.0f);
    const float inv = 1.0f / fmaxf(sqrtf(var), EPS);

    // ---- normalize ALL frames in-register, nontemporal store ----
    #pragma unroll
    for (int it = 0; it < VPT; ++it) {
        const int idx = tid + it * BLOCK;
        if (idx < TV) {
            v4f o;
            #pragma unroll
            for (int j = 0; j < 4; ++j)
                o[j] = (v[it][j] - mean) * inv;
            __builtin_nontemporal_store(o, &outr[idx]);
        }
    }
}

extern "C" void kernel_launch(void* const* d_in, const int* in_sizes, int n_in,
                              void* d_out, int out_size, void* d_ws, size_t ws_size,
                              hipStream_t stream) {
    const float* x = (const float*)d_in[0];
    const float* lengths = (const float*)d_in[1];
    float* out = (float*)d_out;

    const int B = in_sizes[1];                     // 64
    const int F = in_sizes[0] / (B * ROW_T);       // 80
    const int rows = B * F;                        // 5120 blocks

    isn_kernel<<<rows, BLOCK, 0, stream>>>(x, lengths, out, F);
}